// Round 1
// baseline (876.526 us; speedup 1.0000x reference)
//
#include <hip/hip_runtime.h>

// TTGNN: 2-layer GAT-style transformer conv, N=20000, E=120000, D=1024, H=8, C=128.
// R4: attention kernel redesigned as wave-per-node (lane owns 16 channels).
// R5: (a) XCD-aware block swizzle in gemm_bf16 (T1: consecutive same-bm blocks
//     share a 256KB A-panel; keep them on one XCD's L2). Grids 2512/1256 are
//     divisible by 8 so the simple bijective swizzle applies.
//     (b) m_kernel rewritten: all 5 edge types in one W_e pass (load once,
//     5 FMAs), k split 4-way across waves + deterministic LDS reduce.

#define NN 20000
#define NE 120000
#define DD 1024
#define NH 8

typedef __attribute__((ext_vector_type(4))) float f32x4;
typedef __bf16 bf16x8 __attribute__((ext_vector_type(8)));

__device__ __forceinline__ unsigned short f2bf(float f) {
  unsigned int u = __float_as_uint(f);
  u += 0x7FFFu + ((u >> 16) & 1u);   // round-to-nearest-even
  return (unsigned short)(u >> 16);
}
__device__ __forceinline__ float bf2f(unsigned short u) {
  return __uint_as_float((unsigned int)u << 16);
}
__device__ __forceinline__ void unpack8(uint4 u, float* f) {
  f[0] = __uint_as_float(u.x << 16); f[1] = __uint_as_float(u.x & 0xFFFF0000u);
  f[2] = __uint_as_float(u.y << 16); f[3] = __uint_as_float(u.y & 0xFFFF0000u);
  f[4] = __uint_as_float(u.z << 16); f[5] = __uint_as_float(u.z & 0xFFFF0000u);
  f[6] = __uint_as_float(u.w << 16); f[7] = __uint_as_float(u.w & 0xFFFF0000u);
}

// ---------------- CSR build ----------------

__global__ __launch_bounds__(256) void count_kernel(
    const int* __restrict__ EI, const int* __restrict__ eattr, int* __restrict__ cnt) {
  int e = blockIdx.x * 256 + threadIdx.x;
  if (e < NE) {
    int d = EI[NE + e];
    int t = eattr[e];
    atomicAdd(&cnt[d * 5 + t], 1);
  }
}

__global__ __launch_bounds__(1024) void scan_kernel(
    const int* __restrict__ cnt, int* __restrict__ rowptr, int* __restrict__ cursor) {
  __shared__ int wsum[16];
  __shared__ int carry_s;
  int tid = threadIdx.x, lane = tid & 63, wv = tid >> 6;
  if (tid == 0) carry_s = 0;
  __syncthreads();
  for (int base = 0; base < NN; base += 1024) {
    int n = base + tid;
    int d = 0;
    if (n < NN) {
      const int* c = cnt + n * 5;
      d = c[0] + c[1] + c[2] + c[3] + c[4];
    }
    int v = d;
    #pragma unroll
    for (int off = 1; off < 64; off <<= 1) {
      int t = __shfl_up(v, off);
      if (lane >= off) v += t;
    }
    if (lane == 63) wsum[wv] = v;
    __syncthreads();
    int woff = 0;
    #pragma unroll
    for (int w = 0; w < 16; ++w) if (w < wv) woff += wsum[w];
    int carry = carry_s;
    int excl = carry + woff + v - d;
    if (n < NN) { rowptr[n] = excl; cursor[n] = excl; }
    __syncthreads();
    if (tid == 0) {
      int t = 0;
      #pragma unroll
      for (int w = 0; w < 16; ++w) t += wsum[w];
      carry_s = carry + t;
    }
    __syncthreads();
  }
  if (tid == 0) rowptr[NN] = carry_s;
}

__global__ __launch_bounds__(256) void scatter_kernel(
    const int* __restrict__ EI, int* __restrict__ cursor, int* __restrict__ eids) {
  int e = blockIdx.x * 256 + threadIdx.x;
  if (e < NE) {
    int d = EI[NE + e];
    int pos = atomicAdd(&cursor[d], 1);
    eids[pos] = e;
  }
}

// ---------------- h0 = x + node_type_emb[node_types] ----------------

__global__ __launch_bounds__(256) void init_h_kernel(
    const float* __restrict__ x, const int* __restrict__ ntypes,
    const float* __restrict__ ntemb, float* __restrict__ h,
    unsigned short* __restrict__ hb) {
  int idx = blockIdx.x * 256 + threadIdx.x;
  int n = idx >> 8;
  int d4 = idx & 255;
  int t = ntypes[n];
  float4 xv = ((const float4*)x)[idx];
  float4 ev = ((const float4*)ntemb)[t * 256 + d4];
  float4 o;
  o.x = xv.x + ev.x; o.y = xv.y + ev.y; o.z = xv.z + ev.z; o.w = xv.w + ev.w;
  ((float4*)h)[idx] = o;
  ushort4 hv;
  hv.x = f2bf(o.x); hv.y = f2bf(o.y); hv.z = f2bf(o.z); hv.w = f2bf(o.w);
  ((ushort4*)hb)[idx] = hv;
}

// ---------------- weight transpose + bf16: WT[n][k] = bf16(W[k][n]) ----------------

__global__ __launch_bounds__(256) void transpose_w_kernel(
    const float* __restrict__ W, unsigned short* __restrict__ WT) {
  __shared__ float tile[32][33];
  int tx = threadIdx.x & 31, ty = threadIdx.x >> 5;
  int bx = blockIdx.x * 32;   // n base
  int by = blockIdx.y * 32;   // k base
  #pragma unroll
  for (int r = 0; r < 4; ++r)
    tile[ty + r * 8][tx] = W[(size_t)(by + ty + r * 8) * DD + bx + tx];
  __syncthreads();
  #pragma unroll
  for (int r = 0; r < 4; ++r)
    WT[(size_t)(bx + ty + r * 8) * DD + by + tx] = f2bf(tile[tx][ty + r * 8]);
}

// ---------------- M[t] = edge_type_emb[t] @ W_e[l]   (5 x 1024) ----------------
// R5: one pass over W_e (each value loaded once, used for all 5 types);
// k split 4-way across the block's 4 waves, deterministic LDS reduce.
// grid: (DD/64) blocks x 256 threads; thread = (kc = tid>>6, jl = tid&63).

__global__ __launch_bounds__(256) void m_kernel(
    const float* __restrict__ ete, const float* __restrict__ We, float* __restrict__ M) {
  __shared__ float red[4][5][64];
  const int jl = threadIdx.x & 63;
  const int kc = threadIdx.x >> 6;          // wave-uniform
  const int j = blockIdx.x * 64 + jl;
  float acc[5] = {0.f, 0.f, 0.f, 0.f, 0.f};
  const int k0 = kc * 256;
  for (int k = k0; k < k0 + 256; ++k) {
    float w = We[(size_t)k * DD + j];
    #pragma unroll
    for (int t = 0; t < 5; ++t) acc[t] += ete[t * DD + k] * w;
  }
  #pragma unroll
  for (int t = 0; t < 5; ++t) red[kc][t][jl] = acc[t];
  __syncthreads();
  if (threadIdx.x < 64) {
    #pragma unroll
    for (int t = 0; t < 5; ++t)
      M[t * DD + blockIdx.x * 64 + threadIdx.x] =
          red[0][t][threadIdx.x] + red[1][t][threadIdx.x] +
          red[2][t][threadIdx.x] + red[3][t][threadIdx.x];
  }
}

// ---------------- bf16 MFMA GEMM, global_load_lds staging (m97 structure) ----
// A: bf16 [M][1024].  BT: bf16 [Ncols][1024] (B transposed), Ncols = 128*gridDim.x.
// mode 0 (dual): bn<8 -> bf16 C0b (+bias0), bn>=8 -> bf16 C1b (+bias1).
// mode 1 (final): fp32 C = resid + gate*(acc + bias0).
// R5: XCD-aware swizzle of the linearized block id (grid sizes are % 8 == 0).

__global__ __launch_bounds__(256) void gemm_bf16(
    const unsigned short* __restrict__ A, const unsigned short* __restrict__ BT,
    const float* __restrict__ bias0, const float* __restrict__ bias1,
    void* __restrict__ C0v, void* __restrict__ C1v,
    const float* __restrict__ resid, const float* __restrict__ gatep,
    int M, int mode) {
  __shared__ unsigned short lsA[128 * 32];
  __shared__ unsigned short lsB[128 * 32];
  const int tid = threadIdx.x;
  const int lane = tid & 63;
  const int wv = tid >> 6;
  const int wm = wv & 1, wn = wv >> 1;

  // T1: XCD swizzle. nwg % 8 == 0 for both launch shapes (2512, 1256).
  const int nwg = gridDim.x * gridDim.y;
  const int lid = blockIdx.y * gridDim.x + blockIdx.x;
  const int cpx = nwg >> 3;
  const int swz = (lid & 7) * cpx + (lid >> 3);
  const int bm = swz / gridDim.x, bn = swz % gridDim.x;

  const int row0 = bm * 128, col0 = bn * 128;
  const int l15 = lane & 15, quad = lane >> 4;

  f32x4 acc[4][4];
  #pragma unroll
  for (int mt = 0; mt < 4; ++mt)
    #pragma unroll
    for (int nt = 0; nt < 4; ++nt) {
      f32x4 z = {0.f, 0.f, 0.f, 0.f};
      acc[mt][nt] = z;
    }

  const int r_in = lane >> 2;            // 0..15
  const int kchunk = (lane & 3) * 8;     // bf16-element offset within 32-wide K

  for (int kk = 0; kk < DD; kk += 32) {
    #pragma unroll
    for (int j = 0; j < 2; ++j) {
      int r = wv * 32 + j * 16;                  // wave-uniform row base
      int gr = row0 + r + r_in;
      if (gr > M - 1) gr = M - 1;                // clamp tail (masked at store)
      const unsigned short* gpA = A + (size_t)gr * DD + kk + kchunk;
      __builtin_amdgcn_global_load_lds(
          (const __attribute__((address_space(1))) unsigned int*)gpA,
          (__attribute__((address_space(3))) unsigned int*)(lsA + r * 32), 16, 0, 0);
      const unsigned short* gpB = BT + (size_t)(col0 + r + r_in) * DD + kk + kchunk;
      __builtin_amdgcn_global_load_lds(
          (const __attribute__((address_space(1))) unsigned int*)gpB,
          (__attribute__((address_space(3))) unsigned int*)(lsB + r * 32), 16, 0, 0);
    }
    __syncthreads();
    bf16x8 af[4], bfr[4];
    #pragma unroll
    for (int mt = 0; mt < 4; ++mt)
      af[mt] = *(const bf16x8*)(lsA + (wm * 64 + mt * 16 + l15) * 32 + quad * 8);
    #pragma unroll
    for (int nt = 0; nt < 4; ++nt)
      bfr[nt] = *(const bf16x8*)(lsB + (wn * 64 + nt * 16 + l15) * 32 + quad * 8);
    #pragma unroll
    for (int mt = 0; mt < 4; ++mt)
      #pragma unroll
      for (int nt = 0; nt < 4; ++nt)
        acc[mt][nt] = __builtin_amdgcn_mfma_f32_16x16x32_bf16(af[mt], bfr[nt], acc[mt][nt], 0, 0, 0);
    __syncthreads();
  }

  if (mode == 0) {
    unsigned short* Cb = (unsigned short*)(bn < 8 ? C0v : C1v);
    const float* bp = (bn < 8) ? bias0 : bias1;
    int coff = (bn < 8) ? 0 : 1024;
    #pragma unroll
    for (int mt = 0; mt < 4; ++mt) {
      #pragma unroll
      for (int r = 0; r < 4; ++r) {
        int grow = row0 + wm * 64 + mt * 16 + quad * 4 + r;
        if (grow >= M) continue;
        #pragma unroll
        for (int nt = 0; nt < 4; ++nt) {
          int c = col0 - coff + wn * 64 + nt * 16 + l15;
          Cb[(size_t)grow * DD + c] = f2bf(acc[mt][nt][r] + bp[c]);
        }
      }
    }
  } else {
    float* Cp = (float*)C0v;
    float g = gatep[0];
    #pragma unroll
    for (int mt = 0; mt < 4; ++mt) {
      #pragma unroll
      for (int r = 0; r < 4; ++r) {
        int grow = row0 + wm * 64 + mt * 16 + quad * 4 + r;
        if (grow >= M) continue;
        #pragma unroll
        for (int nt = 0; nt < 4; ++nt) {
          int c = col0 + wn * 64 + nt * 16 + l15;
          float v = acc[mt][nt][r] + bias0[c];
          Cp[(size_t)grow * DD + c] = resid[(size_t)grow * DD + c] + g * v;
        }
      }
    }
  }
}

// ---------------- fused attention, wave-per-node ----------------
// Block = 256 threads = 4 independent waves; wave handles node n, lane owns
// channels [lane*16, lane*16+16). Softmax computed without max-subtraction
// (shift-invariant; logits bounded by construction), so den/acc are plain sums.
// Head of a lane = lane>>3 (8 lanes per head); logit reduce = 3 xor-shuffles.

__global__ __launch_bounds__(256) void attn_kernel(
    const unsigned short* __restrict__ xlb, const unsigned short* __restrict__ xrb,
    const int* __restrict__ EI, const int* __restrict__ eattr,
    const int* __restrict__ rowptr, const int* __restrict__ eids,
    const int* __restrict__ cnt, const float* __restrict__ Mbuf,
    const float* __restrict__ attl, const float* __restrict__ biasl,
    const float* __restrict__ gammal, const float* __restrict__ betal,
    float* __restrict__ h, unsigned short* __restrict__ hb) {
  const int lane = threadIdx.x & 63;
  const int wv = threadIdx.x >> 6;
  const int n = blockIdx.x * 4 + wv;
  if (n >= NN) return;
  const int ch = lane * 16;

  float xrf[16], attf[16];
  {
    const uint4* xp = (const uint4*)(xrb + (size_t)n * DD + ch);
    uint4 a = xp[0], b = xp[1];
    unpack8(a, xrf); unpack8(b, xrf + 8);
    const float4* ap = (const float4*)(attl + ch);
    #pragma unroll
    for (int q = 0; q < 4; ++q) {
      float4 t = ap[q];
      attf[q * 4 + 0] = t.x; attf[q * 4 + 1] = t.y;
      attf[q * 4 + 2] = t.z; attf[q * 4 + 3] = t.w;
    }
  }
  float acc[16];
  #pragma unroll
  for (int c = 0; c < 16; ++c) acc[c] = 0.f;
  float den = 0.f;

  const int beg = rowptr[n], end = rowptr[n + 1];
  for (int base = beg; base < end; base += 64) {
    int cc = min(64, end - base);
    int packed = 0;
    if (lane < cc) {
      int eid = eids[base + lane];
      packed = (EI[eid] << 3) | eattr[eid];
    }
    for (int j = 0; j < cc; ++j) {
      int pk = __shfl(packed, j);
      int src = pk >> 3, at = pk & 7;
      const uint4* vp = (const uint4*)(xlb + (size_t)src * DD + ch);
      uint4 v0 = vp[0], v1 = vp[1];
      const float4* mp = (const float4*)(Mbuf + at * DD + ch);
      float vf[16];
      unpack8(v0, vf); unpack8(v1, vf + 8);
      float lg = 0.f;
      #pragma unroll
      for (int q = 0; q < 4; ++q) {
        float4 m = mp[q];
        float s0 = vf[q * 4 + 0] + xrf[q * 4 + 0] + m.x; s0 = fmaxf(s0, 0.2f * s0);
        float s1 = vf[q * 4 + 1] + xrf[q * 4 + 1] + m.y; s1 = fmaxf(s1, 0.2f * s1);
        float s2 = vf[q * 4 + 2] + xrf[q * 4 + 2] + m.z; s2 = fmaxf(s2, 0.2f * s2);
        float s3 = vf[q * 4 + 3] + xrf[q * 4 + 3] + m.w; s3 = fmaxf(s3, 0.2f * s3);
        lg += s0 * attf[q * 4 + 0] + s1 * attf[q * 4 + 1]
            + s2 * attf[q * 4 + 2] + s3 * attf[q * 4 + 3];
      }
      lg += __shfl_xor(lg, 1);
      lg += __shfl_xor(lg, 2);
      lg += __shfl_xor(lg, 4);
      float p = __expf(lg);
      den += p;
      #pragma unroll
      for (int c = 0; c < 16; ++c) acc[c] += p * vf[c];
    }
  }

  // self-loop: edge emb = mean of incoming edge-type embeddings
  {
    const int* c5 = cnt + n * 5;
    int c0 = c5[0], c1 = c5[1], c2 = c5[2], c3 = c5[3], c4 = c5[4];
    float inv = 1.f / fmaxf((float)(c0 + c1 + c2 + c3 + c4), 1.f);
    float w0 = c0 * inv, w1 = c1 * inv, w2 = c2 * inv, w3 = c3 * inv, w4 = c4 * inv;
    const uint4* vp = (const uint4*)(xlb + (size_t)n * DD + ch);
    uint4 v0 = vp[0], v1 = vp[1];
    float vf[16];
    unpack8(v0, vf); unpack8(v1, vf + 8);
    const float* m0 = Mbuf + 0 * DD + ch;
    const float* m1 = Mbuf + 1 * DD + ch;
    const float* m2 = Mbuf + 2 * DD + ch;
    const float* m3 = Mbuf + 3 * DD + ch;
    const float* m4 = Mbuf + 4 * DD + ch;
    float lg = 0.f;
    #pragma unroll
    for (int c = 0; c < 16; ++c) {
      float ee = w0 * m0[c] + w1 * m1[c] + w2 * m2[c] + w3 * m3[c] + w4 * m4[c];
      float s = vf[c] + xrf[c] + ee;
      s = fmaxf(s, 0.2f * s);
      lg += s * attf[c];
    }
    lg += __shfl_xor(lg, 1);
    lg += __shfl_xor(lg, 2);
    lg += __shfl_xor(lg, 4);
    float p = __expf(lg);
    den += p;
    #pragma unroll
    for (int c = 0; c < 16; ++c) acc[c] += p * vf[c];
  }

  // epilogue: alpha-normalize + bias + ELU + residual + LayerNorm (in-wave)
  float invd = 1.f / den;
  float y[16];
  float s1 = 0.f, s2 = 0.f;
  {
    const float4* bp = (const float4*)(biasl + ch);
    const float4* hp = (const float4*)(h + (size_t)n * DD + ch);
    #pragma unroll
    for (int q = 0; q < 4; ++q) {
      float4 b4 = bp[q];
      float4 h4 = hp[q];
      float o0 = acc[q * 4 + 0] * invd + b4.x;
      float o1 = acc[q * 4 + 1] * invd + b4.y;
      float o2 = acc[q * 4 + 2] * invd + b4.z;
      float o3 = acc[q * 4 + 3] * invd + b4.w;
      o0 = o0 > 0.f ? o0 : (__expf(o0) - 1.f);
      o1 = o1 > 0.f ? o1 : (__expf(o1) - 1.f);
      o2 = o2 > 0.f ? o2 : (__expf(o2) - 1.f);
      o3 = o3 > 0.f ? o3 : (__expf(o3) - 1.f);
      y[q * 4 + 0] = o0 + h4.x; y[q * 4 + 1] = o1 + h4.y;
      y[q * 4 + 2] = o2 + h4.z; y[q * 4 + 3] = o3 + h4.w;
      s1 += y[q * 4 + 0] + y[q * 4 + 1] + y[q * 4 + 2] + y[q * 4 + 3];
      s2 += y[q * 4 + 0] * y[q * 4 + 0] + y[q * 4 + 1] * y[q * 4 + 1]
          + y[q * 4 + 2] * y[q * 4 + 2] + y[q * 4 + 3] * y[q * 4 + 3];
    }
  }
  #pragma unroll
  for (int off = 1; off < 64; off <<= 1) {
    s1 += __shfl_xor(s1, off);
    s2 += __shfl_xor(s2, off);
  }
  float mu = s1 * (1.f / 1024.f);
  float var = s2 * (1.f / 1024.f) - mu * mu;
  float rs = rsqrtf(var + 1e-5f);
  {
    const float4* gp = (const float4*)(gammal + ch);
    const float4* bp = (const float4*)(betal + ch);
    float4* hp = (float4*)(h + (size_t)n * DD + ch);
    uint4* hbp = (uint4*)(hb + (size_t)n * DD + ch);
    uint4 pk0, pk1;
    unsigned int* pk = (unsigned int*)&pk0;
    #pragma unroll
    for (int q = 0; q < 4; ++q) {
      float4 g4 = gp[q];
      float4 b4 = bp[q];
      float4 o4;
      o4.x = (y[q * 4 + 0] - mu) * rs * g4.x + b4.x;
      o4.y = (y[q * 4 + 1] - mu) * rs * g4.y + b4.y;
      o4.z = (y[q * 4 + 2] - mu) * rs * g4.z + b4.z;
      o4.w = (y[q * 4 + 3] - mu) * rs * g4.w + b4.w;
      hp[q] = o4;
      unsigned int lo = (unsigned int)f2bf(o4.x) | ((unsigned int)f2bf(o4.y) << 16);
      unsigned int hi = (unsigned int)f2bf(o4.z) | ((unsigned int)f2bf(o4.w) << 16);
      if (q < 2) { pk[q * 2] = lo; pk[q * 2 + 1] = hi; }
      else {
        unsigned int* pkh = (unsigned int*)&pk1;
        pkh[(q - 2) * 2] = lo; pkh[(q - 2) * 2 + 1] = hi;
      }
    }
    hbp[0] = pk0;
    hbp[1] = pk1;
  }
}

// ---------------- launcher ----------------

extern "C" void kernel_launch(void* const* d_in, const int* in_sizes, int n_in,
                              void* d_out, int out_size, void* d_ws, size_t ws_size,
                              hipStream_t stream) {
  (void)in_sizes; (void)n_in; (void)out_size; (void)ws_size;
  const float* x      = (const float*)d_in[0];
  const int*   EI     = (const int*)d_in[1];
  const int*   eattr  = (const int*)d_in[2];
  const int*   ntypes = (const int*)d_in[3];
  const float* ntemb  = (const float*)d_in[4];
  const float* etemb  = (const float*)d_in[5];
  const float* W_l    = (const float*)d_in[6];
  const float* b_l    = (const float*)d_in[7];
  const float* W_r    = (const float*)d_in[8];
  const float* b_r    = (const float*)d_in[9];
  const float* W_e    = (const float*)d_in[10];
  const float* att    = (const float*)d_in[11];
  const float* bias   = (const float*)d_in[12];
  const float* gamma  = (const float*)d_in[13];
  const float* beta   = (const float*)d_in[14];
  const float* W_out  = (const float*)d_in[15];
  const float* b_out  = (const float*)d_in[16];
  const float* gate   = (const float*)d_in[17];
  float* out = (float*)d_out;

  char* ws = (char*)d_ws;
  size_t off = 0;
  auto alloc = [&](size_t bytes) {
    char* p = ws + off;
    off = (off + bytes + 255) & ~(size_t)255;
    return p;
  };
  float*          h       = (float*)alloc((size_t)NN * DD * 4);
  unsigned short* hb      = (unsigned short*)alloc((size_t)NN * DD * 2);
  unsigned short* xlb     = (unsigned short*)alloc((size_t)NN * DD * 2);
  unsigned short* xrb     = (unsigned short*)alloc((size_t)NN * DD * 2);
  unsigned short* WTcat   = (unsigned short*)alloc((size_t)2 * DD * DD * 2);  // [W_l^T ; W_r^T]
  unsigned short* WT2     = (unsigned short*)alloc((size_t)DD * DD * 2);
  float*          Mbuf    = (float*)alloc((size_t)5 * DD * 4);
  int*            countb  = (int*)alloc((size_t)NN * 5 * 4);
  int*            rowptr  = (int*)alloc((size_t)(NN + 1) * 4);
  int*            cursor  = (int*)alloc((size_t)NN * 4);
  int*            eids    = (int*)alloc((size_t)NE * 4);

  hipMemsetAsync(countb, 0, (size_t)NN * 5 * 4, stream);
  count_kernel<<<(NE + 255) / 256, 256, 0, stream>>>(EI, eattr, countb);
  scan_kernel<<<1, 1024, 0, stream>>>(countb, rowptr, cursor);
  scatter_kernel<<<(NE + 255) / 256, 256, 0, stream>>>(EI, cursor, eids);
  init_h_kernel<<<NN, 256, 0, stream>>>(x, ntypes, ntemb, h, hb);

  dim3 tgrid(DD / 32, DD / 32);
  dim3 ggrid2(16, (NN + 127) / 128);   // dual GEMM: N=2048, 2512 blocks (%8==0)
  dim3 ggrid1(8, (NN + 127) / 128);    // final GEMM: N=1024, 1256 blocks (%8==0)
  for (int l = 0; l < 2; ++l) {
    transpose_w_kernel<<<tgrid, 256, 0, stream>>>(W_l + (size_t)l * DD * DD, WTcat);
    transpose_w_kernel<<<tgrid, 256, 0, stream>>>(W_r + (size_t)l * DD * DD, WTcat + (size_t)DD * DD);
    m_kernel<<<DD / 64, 256, 0, stream>>>(etemb, W_e + (size_t)l * DD * DD, Mbuf);
    gemm_bf16<<<ggrid2, 256, 0, stream>>>(hb, WTcat, b_l + l * DD, b_r + l * DD,
                                          xlb, xrb, nullptr, nullptr, NN, 0);
    attn_kernel<<<(NN + 3) / 4, 256, 0, stream>>>(xlb, xrb, EI, eattr, rowptr, eids, countb, Mbuf,
                                                  att + l * DD, bias + l * DD,
                                                  gamma + l * DD, beta + l * DD, h, hb);
  }
  transpose_w_kernel<<<tgrid, 256, 0, stream>>>(W_out, WT2);
  gemm_bf16<<<ggrid1, 256, 0, stream>>>(hb, WT2, b_out, nullptr,
                                        out, nullptr, x, gate, NN, 1);
}